// Round 9
// baseline (361.012 us; speedup 1.0000x reference)
//
#include <hip/hip_runtime.h>
#include <hip/hip_bf16.h>

// B=8, N=4096, D=H=256. out[b,h] = sum_k w[b,k]*V[b,k,h],
//   w[b,k] = (1/N) sum_q exp(scale*s_qk)/l_q,  l_q = sum_k exp(scale*s_qk)
// R8 = R7 with the compile fix: no local arrays of LDS pointers (gfx950
//     addrspacecast static-initializer error); buffers selected by offset math.
//     2-deep DMA pipeline, flat 16-step loop, stage(s+1) before compute(s),
//     one barrier/step. LDS 64KB (still 2 blocks/CU - VGPR-capped).

#define NTOK 4096
#define HDIM 256
#define NBATCH 8
#define SCALE 0.0625f  // 1/sqrt(256)

typedef __attribute__((ext_vector_type(8))) short short8_t;   // 8 bf16 (4 VGPRs)
typedef __attribute__((ext_vector_type(16))) float f32x16;    // 32x32 C/D frag

__device__ __forceinline__ unsigned short f2bf(float f) {
    unsigned u = __float_as_uint(f);
    u += 0x7fff + ((u >> 16) & 1);   // RNE
    return (unsigned short)(u >> 16);
}

#define MFMA(a, b, c) __builtin_amdgcn_mfma_f32_32x32x16_bf16(a, b, c, 0, 0, 0)

__device__ __forceinline__ void async_cp16(const void* g, void* l) {
    __builtin_amdgcn_global_load_lds((const __attribute__((address_space(1))) void*)g,
                                     (__attribute__((address_space(3))) void*)l, 16, 0, 0);
}

// Stage 128 rows x 64 bf16 cols into swizzled LDS: unit (r,u) -> r*8 + (u^(r&7)).
__device__ __forceinline__ void stage_swz(unsigned short* lds, const unsigned short* src,
                                          int row0, int dbase, int w, int l) {
#pragma unroll
    for (int i = 0; i < 4; ++i) {
        int rloc = w * 32 + i * 8 + (l >> 3);
        int u = (l & 7) ^ (l >> 3);
        const unsigned short* g = src + (size_t)(row0 + rloc) * HDIM + dbase + u * 8;
        unsigned short* d = lds + (w * 32 + i * 8) * 64;
        async_cp16(g, d);
    }
}

__device__ __forceinline__ short8_t frd(const unsigned short* lds, int rb, int lo, int u) {
    return *(const short8_t*)(lds + ((rb * 32 + lo) * 8 + (u ^ (lo & 7))) * 8);
}

__global__ void zero_kernel(float* __restrict__ w, float* __restrict__ l, float* __restrict__ out) {
    int i = blockIdx.x * 256 + threadIdx.x;
    w[i] = 0.f;
    l[i] = 0.f;
    if (i < NBATCH * HDIM) out[i] = 0.f;
}

__global__ void convert_wt(const float* __restrict__ Wq, const float* __restrict__ Wk,
                           const float* __restrict__ Wv, unsigned short* __restrict__ Wt) {
    int z = blockIdx.y;
    const float* W = (z == 0) ? Wq : (z == 1) ? Wk : Wv;
    unsigned short* o = Wt + z * 65536;
    int n = threadIdx.x;
    for (int kk = 0; kk < 32; ++kk) {
        int k = blockIdx.x * 32 + kk;
        o[n * 256 + k] = f2bf(W[k * 256 + n]);
    }
}

__device__ __forceinline__ void stage_tile(unsigned short* __restrict__ dst,
                                           const unsigned short* __restrict__ src,
                                           int row0, int dbase, int t) {
#pragma unroll
    for (int i = 0; i < 4; ++i) {
        int f = t + i * 256;
        int r = f >> 3;
        int c8 = (f & 7) * 8;
        *(uint4*)(dst + r * 72 + c8) = *(const uint4*)(src + (size_t)(row0 + r) * HDIM + dbase + c8);
    }
}

__global__ __launch_bounds__(256) void qkv_mfma(const float* __restrict__ x,
                                                const unsigned short* __restrict__ Wt,
                                                const float* __restrict__ bq, const float* __restrict__ bk,
                                                const float* __restrict__ bv,
                                                unsigned short* __restrict__ Qbf,
                                                unsigned short* __restrict__ Kbf,
                                                float* __restrict__ Vf) {
    const int z = blockIdx.z;
    const unsigned short* Wz = Wt + z * 65536;
    const float* bias = (z == 0) ? bq : (z == 1) ? bk : bv;
    const int m0 = blockIdx.x * 128, n0 = blockIdx.y * 128;
    const int t = threadIdx.x, wv_ = t >> 6, l = t & 63, lo = l & 31, hi = l >> 5;
    const int wq = (wv_ & 1) * 64, wk = (wv_ >> 1) * 64;

    __shared__ __align__(16) char smem[36864];
    unsigned short* Xs = (unsigned short*)smem;
    unsigned short* Ws = Xs + 128 * 72;

    f32x16 acc[2][2];
#pragma unroll
    for (int a = 0; a < 2; ++a)
#pragma unroll
        for (int b = 0; b < 2; ++b)
#pragma unroll
            for (int r = 0; r < 16; ++r) acc[a][b][r] = 0.f;

    for (int dc = 0; dc < 4; ++dc) {
        __syncthreads();
#pragma unroll
        for (int i = 0; i < 4; ++i) {
            int f = t + i * 256;
            int r = f >> 3;
            int c8 = (f & 7) * 8;
            const float* s = x + (size_t)(m0 + r) * HDIM + dc * 64 + c8;
            float4 v0 = *(const float4*)s;
            float4 v1 = *(const float4*)(s + 4);
            short8_t o;
            o[0] = (short)f2bf(v0.x); o[1] = (short)f2bf(v0.y);
            o[2] = (short)f2bf(v0.z); o[3] = (short)f2bf(v0.w);
            o[4] = (short)f2bf(v1.x); o[5] = (short)f2bf(v1.y);
            o[6] = (short)f2bf(v1.z); o[7] = (short)f2bf(v1.w);
            *(short8_t*)(Xs + r * 72 + c8) = o;
        }
        stage_tile(Ws, Wz, n0, dc * 64, t);
        __syncthreads();
#pragma unroll
        for (int ks = 0; ks < 4; ++ks) {
            int kidx = ks * 16 + hi * 8;
            short8_t a0 = *(const short8_t*)(Xs + (wq + lo) * 72 + kidx);
            short8_t a1 = *(const short8_t*)(Xs + (wq + 32 + lo) * 72 + kidx);
            short8_t b0 = *(const short8_t*)(Ws + (wk + lo) * 72 + kidx);
            short8_t b1 = *(const short8_t*)(Ws + (wk + 32 + lo) * 72 + kidx);
            acc[0][0] = MFMA(a0, b0, acc[0][0]);
            acc[0][1] = MFMA(a0, b1, acc[0][1]);
            acc[1][0] = MFMA(a1, b0, acc[1][0]);
            acc[1][1] = MFMA(a1, b1, acc[1][1]);
        }
    }
    float bc0 = bias[n0 + wk + lo];
    float bc1 = bias[n0 + wk + 32 + lo];
#pragma unroll
    for (int mb = 0; mb < 2; ++mb)
#pragma unroll
        for (int r = 0; r < 16; ++r) {
            int row = m0 + wq + mb * 32 + (r & 3) + 8 * (r >> 2) + 4 * hi;
            int c0 = n0 + wk + lo, c1 = n0 + wk + 32 + lo;
            float v0 = acc[mb][0][r] + bc0;
            float v1 = acc[mb][1][r] + bc1;
            if (z == 2) {
                Vf[(size_t)row * HDIM + c0] = v0;
                Vf[(size_t)row * HDIM + c1] = v1;
            } else {
                unsigned short* o = (z == 0) ? Qbf : Kbf;
                o[(size_t)row * HDIM + c0] = f2bf(v0);
                o[(size_t)row * HDIM + c1] = f2bf(v1);
            }
        }
}

// ---------------- pass 1: l[b,q] = sum_k exp(scale*s) ----------------
// 128 q rows/block, streams 512 k. 2-deep DMA pipeline, 1 barrier/step.
__global__ __launch_bounds__(256) void score_pass1(const unsigned short* __restrict__ Qbf,
                                                   const unsigned short* __restrict__ Kbf,
                                                   float* __restrict__ lsum) {
    const int b = blockIdx.z;
    const int q0 = blockIdx.x * 128;
    const int kbase = blockIdx.y * 512;
    const int t = threadIdx.x, w = t >> 6, l = t & 63, lo = l & 31, hi = l >> 5;
    const int rq = (w & 1) * 2, rk = (w >> 1) * 2;
    const unsigned short* Qb = Qbf + (size_t)b * NTOK * HDIM;
    const unsigned short* Kb = Kbf + (size_t)b * NTOK * HDIM;

    __shared__ __align__(16) char smem[65536];   // Q0|Q1|K0|K1 16KB each; red overlays
    float* red = (float*)smem;                    // [128][66] = 33792 B

    float rs[2][16];
#pragma unroll
    for (int mb = 0; mb < 2; ++mb)
#pragma unroll
        for (int r = 0; r < 16; ++r) rs[mb][r] = 0.f;

    f32x16 acc[2][2];

    stage_swz((unsigned short*)smem, Qb, q0, 0, w, l);
    stage_swz((unsigned short*)(smem + 32768), Kb, kbase, 0, w, l);
    __syncthreads();

    for (int s = 0; s < 16; ++s) {
        const int dc = s & 3;
        if (dc == 0) {
#pragma unroll
            for (int a = 0; a < 2; ++a)
#pragma unroll
                for (int c = 0; c < 2; ++c)
#pragma unroll
                    for (int r = 0; r < 16; ++r) acc[a][c][r] = 0.f;
        }
        if (s + 1 < 16) {
            const int s1 = s + 1, kt1 = s1 >> 2, dc1 = s1 & 3;
            stage_swz((unsigned short*)(smem + (s1 & 1) * 16384), Qb, q0, dc1 * 64, w, l);
            stage_swz((unsigned short*)(smem + 32768 + (s1 & 1) * 16384), Kb,
                      kbase + kt1 * 128, dc1 * 64, w, l);
        }
        const unsigned short* Qs = (const unsigned short*)(smem + (s & 1) * 16384);
        const unsigned short* Ks = (const unsigned short*)(smem + 32768 + (s & 1) * 16384);
#pragma unroll
        for (int ks = 0; ks < 4; ++ks) {
            int u = ks * 2 + hi;
            short8_t a0 = frd(Qs, rq + 0, lo, u);
            short8_t a1 = frd(Qs, rq + 1, lo, u);
            short8_t b0 = frd(Ks, rk + 0, lo, u);
            short8_t b1 = frd(Ks, rk + 1, lo, u);
            acc[0][0] = MFMA(a0, b0, acc[0][0]);
            acc[0][1] = MFMA(a0, b1, acc[0][1]);
            acc[1][0] = MFMA(a1, b0, acc[1][0]);
            acc[1][1] = MFMA(a1, b1, acc[1][1]);
        }
        if (dc == 3) {
#pragma unroll
            for (int mb = 0; mb < 2; ++mb)
#pragma unroll
                for (int r = 0; r < 16; ++r)
                    rs[mb][r] += __expf(acc[mb][0][r] * SCALE) + __expf(acc[mb][1][r] * SCALE);
        }
        __syncthreads();
    }
#pragma unroll
    for (int mb = 0; mb < 2; ++mb)
#pragma unroll
        for (int r = 0; r < 16; ++r) {
            int row = (w & 1) * 64 + mb * 32 + (r & 3) + 8 * (r >> 2) + 4 * hi;
            red[row * 66 + (w >> 1) * 32 + lo] = rs[mb][r];
        }
    __syncthreads();
    if (t < 128) {
        float s = 0.f;
#pragma unroll 8
        for (int j = 0; j < 64; ++j) s += red[t * 66 + j];
        atomicAdd(&lsum[b * NTOK + q0 + t], s);
    }
}

// ---------------- pass 2: w[b,k] += sum_q exp(scale*s)/l_q ----------------
__global__ __launch_bounds__(256) void score_pass2(const unsigned short* __restrict__ Qbf,
                                                   const unsigned short* __restrict__ Kbf,
                                                   const float* __restrict__ lsum,
                                                   float* __restrict__ wsum) {
    const int b = blockIdx.z;
    const int k0 = blockIdx.x * 128;
    const int qbase = blockIdx.y * 512;
    const int t = threadIdx.x, w = t >> 6, l = t & 63, lo = l & 31, hi = l >> 5;
    const int rq = (w & 1) * 2, rk = (w >> 1) * 2;
    const unsigned short* Qb = Qbf + (size_t)b * NTOK * HDIM;
    const unsigned short* Kb = Kbf + (size_t)b * NTOK * HDIM;

    __shared__ __align__(16) char smem[65536];
    __shared__ float linv_s[2][128];
    float* red2 = (float*)smem;

    float cs0 = 0.f, cs1 = 0.f;
    f32x16 acc[2][2];

    stage_swz((unsigned short*)smem, Qb, qbase, 0, w, l);
    stage_swz((unsigned short*)(smem + 32768), Kb, k0, 0, w, l);
    if (t < 128) linv_s[0][t] = 1.0f / lsum[b * NTOK + qbase + t];
    __syncthreads();

    for (int s = 0; s < 16; ++s) {
        const int kt = s >> 2, dc = s & 3;
        if (dc == 0) {
#pragma unroll
            for (int a = 0; a < 2; ++a)
#pragma unroll
                for (int c = 0; c < 2; ++c)
#pragma unroll
                    for (int r = 0; r < 16; ++r) acc[a][c][r] = 0.f;
        }
        if (s + 1 < 16) {
            const int s1 = s + 1, kt1 = s1 >> 2, dc1 = s1 & 3;
            stage_swz((unsigned short*)(smem + (s1 & 1) * 16384), Qb,
                      qbase + kt1 * 128, dc1 * 64, w, l);
            stage_swz((unsigned short*)(smem + 32768 + (s1 & 1) * 16384), Kb,
                      k0, dc1 * 64, w, l);
            if (dc1 == 0 && t < 128)
                linv_s[kt1 & 1][t] = 1.0f / lsum[b * NTOK + qbase + kt1 * 128 + t];
        }
        const unsigned short* Qs = (const unsigned short*)(smem + (s & 1) * 16384);
        const unsigned short* Ks = (const unsigned short*)(smem + 32768 + (s & 1) * 16384);
#pragma unroll
        for (int ks = 0; ks < 4; ++ks) {
            int u = ks * 2 + hi;
            short8_t a0 = frd(Qs, rq + 0, lo, u);
            short8_t a1 = frd(Qs, rq + 1, lo, u);
            short8_t b0 = frd(Ks, rk + 0, lo, u);
            short8_t b1 = frd(Ks, rk + 1, lo, u);
            acc[0][0] = MFMA(a0, b0, acc[0][0]);
            acc[0][1] = MFMA(a0, b1, acc[0][1]);
            acc[1][0] = MFMA(a1, b0, acc[1][0]);
            acc[1][1] = MFMA(a1, b1, acc[1][1]);
        }
        if (dc == 3) {
#pragma unroll
            for (int mb = 0; mb < 2; ++mb)
#pragma unroll
                for (int r = 0; r < 16; ++r) {
                    float li = linv_s[kt & 1][(w & 1) * 64 + mb * 32 + (r & 3) + 8 * (r >> 2) + 4 * hi];
                    cs0 += __expf(acc[mb][0][r] * SCALE) * li;
                    cs1 += __expf(acc[mb][1][r] * SCALE) * li;
                }
        }
        __syncthreads();
    }
    red2[((w >> 1) * 64 + lo) * 5 + (w & 1) * 2 + hi] = cs0;
    red2[((w >> 1) * 64 + 32 + lo) * 5 + (w & 1) * 2 + hi] = cs1;
    __syncthreads();
    if (t < 128) {
        float s = red2[t * 5 + 0] + red2[t * 5 + 1] + red2[t * 5 + 2] + red2[t * 5 + 3];
        atomicAdd(&wsum[b * NTOK + k0 + t], s);
    }
}

__global__ __launch_bounds__(256) void finalize_kernel(const float* __restrict__ V,
                                                       const float* __restrict__ w,
                                                       float* __restrict__ out) {
    const int b = blockIdx.y;
    const int k0 = blockIdx.x * 256;
    const int h = threadIdx.x;
    __shared__ float wsh[256];
    wsh[h] = w[b * NTOK + k0 + h];
    __syncthreads();
    const float* Vb = V + ((size_t)b * NTOK + k0) * HDIM;
    float acc = 0.f;
#pragma unroll 4
    for (int kk = 0; kk < 256; ++kk) acc = fmaf(wsh[kk], Vb[(size_t)kk * HDIM + h], acc);
    atomicAdd(&out[b * HDIM + h], acc * (1.0f / (float)NTOK));
}

extern "C" void kernel_launch(void* const* d_in, const int* in_sizes, int n_in,
                              void* d_out, int out_size, void* d_ws, size_t ws_size,
                              hipStream_t stream) {
    const float* x  = (const float*)d_in[0];
    const float* Wq = (const float*)d_in[1];
    const float* bq = (const float*)d_in[2];
    const float* Wk = (const float*)d_in[3];
    const float* bk = (const float*)d_in[4];
    const float* Wv = (const float*)d_in[5];
    const float* bv = (const float*)d_in[6];
    float* out = (float*)d_out;

    const size_t BNH = (size_t)NBATCH * NTOK * HDIM;
    unsigned short* Wt  = (unsigned short*)d_ws;
    unsigned short* Qbf = Wt + 3 * 65536;
    unsigned short* Kbf = Qbf + BNH;
    float* Vf   = (float*)(Kbf + BNH);
    float* lsum = Vf + BNH;
    float* wsum = lsum + (size_t)NBATCH * NTOK;

    zero_kernel<<<dim3(128), dim3(256), 0, stream>>>(wsum, lsum, out);
    convert_wt<<<dim3(8, 3), dim3(256), 0, stream>>>(Wq, Wk, Wv, Wt);
    qkv_mfma<<<dim3(256, 2, 3), dim3(256), 0, stream>>>(x, Wt, bq, bk, bv, Qbf, Kbf, Vf);
    score_pass1<<<dim3(32, 8, 8), dim3(256), 0, stream>>>(Qbf, Kbf, lsum);
    score_pass2<<<dim3(32, 8, 8), dim3(256), 0, stream>>>(Qbf, Kbf, lsum, wsum);
    finalize_kernel<<<dim3(16, 8), dim3(256), 0, stream>>>(Vf, wsum, out);
}

// Round 11
// 294.620 us; speedup vs baseline: 1.2254x; 1.2254x over previous
//
#include <hip/hip_runtime.h>
#include <hip/hip_bf16.h>

// B=8, N=4096, D=H=256. out[b,h] = sum_k w[b,k]*V[b,k,h],
//   w[b,k] = (1/N) sum_q exp(scale*s_qk)/l_q,  l_q = sum_k exp(scale*s_qk)
// R10: score passes reverted VERBATIM to the R7-validated 310us kernels
//      (stage-per-step DMA, 2 barriers/step — the only pattern that passed
//      post-timing revalidation). R9's persistent-LDS operand raced; dropped.
//      New: qkv rebuilt as a clone of the score-pass engine (x pre-converted
//      to bf16 once; DMA staging; no in-loop f2bf VALU).

#define NTOK 4096
#define HDIM 256
#define NBATCH 8
#define SCALE 0.0625f  // 1/sqrt(256)

typedef __attribute__((ext_vector_type(8))) short short8_t;   // 8 bf16 (4 VGPRs)
typedef __attribute__((ext_vector_type(16))) float f32x16;    // 32x32 C/D frag

__device__ __forceinline__ unsigned short f2bf(float f) {
    unsigned u = __float_as_uint(f);
    u += 0x7fff + ((u >> 16) & 1);   // RNE
    return (unsigned short)(u >> 16);
}

#define MFMA(a, b, c) __builtin_amdgcn_mfma_f32_32x32x16_bf16(a, b, c, 0, 0, 0)

__device__ __forceinline__ void async_cp16(const void* g, void* l) {
    __builtin_amdgcn_global_load_lds((const __attribute__((address_space(1))) void*)g,
                                     (__attribute__((address_space(3))) void*)l, 16, 0, 0);
}

// Stage 128 rows x 64 bf16 cols into swizzled LDS: 16B unit (r,u) -> r*8 + (u^(r&7)).
__device__ __forceinline__ void stage_swz(unsigned short* lds, const unsigned short* src,
                                          int row0, int dbase, int w, int l) {
#pragma unroll
    for (int i = 0; i < 4; ++i) {
        int rloc = w * 32 + i * 8 + (l >> 3);
        int u = (l & 7) ^ (l >> 3);
        const unsigned short* g = src + (size_t)(row0 + rloc) * HDIM + dbase + u * 8;
        unsigned short* d = lds + (w * 32 + i * 8) * 64;
        async_cp16(g, d);
    }
}

__device__ __forceinline__ short8_t frd(const unsigned short* lds, int rb, int lo, int u) {
    return *(const short8_t*)(lds + ((rb * 32 + lo) * 8 + (u ^ (lo & 7))) * 8);
}

__global__ void zero_kernel(float* __restrict__ w, float* __restrict__ l, float* __restrict__ out) {
    int i = blockIdx.x * 256 + threadIdx.x;
    w[i] = 0.f;
    l[i] = 0.f;
    if (i < NBATCH * HDIM) out[i] = 0.f;
}

// ---------------- fp32 -> bf16 for x (once) ----------------
__global__ void convert_x(const float* __restrict__ x, unsigned short* __restrict__ xbf) {
    int i = (blockIdx.x * 256 + threadIdx.x) * 4;
    float4 v = *(const float4*)(x + i);
    ushort4 o;
    o.x = f2bf(v.x); o.y = f2bf(v.y); o.z = f2bf(v.z); o.w = f2bf(v.w);
    *(ushort4*)(xbf + i) = o;
}

__global__ void convert_wt(const float* __restrict__ Wq, const float* __restrict__ Wk,
                           const float* __restrict__ Wv, unsigned short* __restrict__ Wt) {
    int z = blockIdx.y;
    const float* W = (z == 0) ? Wq : (z == 1) ? Wk : Wv;
    unsigned short* o = Wt + z * 65536;
    int n = threadIdx.x;
    for (int kk = 0; kk < 32; ++kk) {
        int k = blockIdx.x * 32 + kk;
        o[n * 256 + k] = f2bf(W[k * 256 + n]);
    }
}

// ---------------- QKV projection: score-pass engine clone ----------------
// out[m][n] = sum_d xbf[m][d]*Wt[n][d] + bias[n]; A=x rows, B=Wt rows.
__global__ __launch_bounds__(256) void qkv_mfma(const unsigned short* __restrict__ xbf,
                                                const unsigned short* __restrict__ Wt,
                                                const float* __restrict__ bq, const float* __restrict__ bk,
                                                const float* __restrict__ bv,
                                                unsigned short* __restrict__ Qbf,
                                                unsigned short* __restrict__ Kbf,
                                                float* __restrict__ Vf) {
    const int z = blockIdx.z;
    const unsigned short* Wz = Wt + z * 65536;
    const float* bias = (z == 0) ? bq : (z == 1) ? bk : bv;
    const int m0 = blockIdx.x * 128, n0 = blockIdx.y * 128;
    const int t = threadIdx.x, w = t >> 6, l = t & 63, lo = l & 31, hi = l >> 5;
    const int rm = (w & 1) * 2, rn = (w >> 1) * 2;

    __shared__ __align__(16) char smem[32768];   // Xb 16K | Wb 16K
    unsigned short* Xb = (unsigned short*)smem;
    unsigned short* Wb = (unsigned short*)(smem + 16384);

    f32x16 acc[2][2];
#pragma unroll
    for (int a = 0; a < 2; ++a)
#pragma unroll
        for (int c = 0; c < 2; ++c)
#pragma unroll
            for (int r = 0; r < 16; ++r) acc[a][c][r] = 0.f;

    for (int dc = 0; dc < 4; ++dc) {
        __syncthreads();
        stage_swz(Xb, xbf, m0, dc * 64, w, l);
        stage_swz(Wb, Wz, n0, dc * 64, w, l);
        __syncthreads();
#pragma unroll
        for (int ks = 0; ks < 4; ++ks) {
            int u = ks * 2 + hi;
            short8_t a0 = frd(Xb, rm + 0, lo, u);
            short8_t a1 = frd(Xb, rm + 1, lo, u);
            short8_t b0 = frd(Wb, rn + 0, lo, u);
            short8_t b1 = frd(Wb, rn + 1, lo, u);
            acc[0][0] = MFMA(a0, b0, acc[0][0]);
            acc[0][1] = MFMA(a0, b1, acc[0][1]);
            acc[1][0] = MFMA(a1, b0, acc[1][0]);
            acc[1][1] = MFMA(a1, b1, acc[1][1]);
        }
    }
    float bc0 = bias[n0 + (w >> 1) * 64 + lo];
    float bc1 = bias[n0 + (w >> 1) * 64 + 32 + lo];
#pragma unroll
    for (int mb = 0; mb < 2; ++mb)
#pragma unroll
        for (int r = 0; r < 16; ++r) {
            int row = m0 + (w & 1) * 64 + mb * 32 + (r & 3) + 8 * (r >> 2) + 4 * hi;
            int c0 = n0 + (w >> 1) * 64 + lo, c1 = c0 + 32;
            float v0 = acc[mb][0][r] + bc0;
            float v1 = acc[mb][1][r] + bc1;
            if (z == 2) {
                Vf[(size_t)row * HDIM + c0] = v0;
                Vf[(size_t)row * HDIM + c1] = v1;
            } else {
                unsigned short* o = (z == 0) ? Qbf : Kbf;
                o[(size_t)row * HDIM + c0] = f2bf(v0);
                o[(size_t)row * HDIM + c1] = f2bf(v1);
            }
        }
}

// ---------------- pass 1 (VERBATIM R7-validated): l[b,q] = sum_k exp(scale*s) ----------------
__global__ __launch_bounds__(256) void score_pass1(const unsigned short* __restrict__ Qbf,
                                                   const unsigned short* __restrict__ Kbf,
                                                   float* __restrict__ lsum) {
    const int b = blockIdx.z;
    const int q0 = blockIdx.x * 128;
    const int kslice = blockIdx.y;
    const int t = threadIdx.x, w = t >> 6, l = t & 63, lo = l & 31, hi = l >> 5;
    const int rq = (w & 1) * 2, rk = (w >> 1) * 2;
    const unsigned short* Qb = Qbf + (size_t)b * NTOK * HDIM;
    const unsigned short* Kb = Kbf + (size_t)b * NTOK * HDIM;

    __shared__ __align__(16) char smem[33792];   // Qs 16K + Ks 16K ; red 128*66*4
    unsigned short* Qs = (unsigned short*)smem;
    unsigned short* Ks = Qs + 8192;
    float* red = (float*)smem;

    float rs[2][16];
#pragma unroll
    for (int mb = 0; mb < 2; ++mb)
#pragma unroll
        for (int r = 0; r < 16; ++r) rs[mb][r] = 0.f;

    for (int kt = 0; kt < 4; ++kt) {
        const int k0 = kslice * 512 + kt * 128;
        f32x16 acc[2][2];
#pragma unroll
        for (int a = 0; a < 2; ++a)
#pragma unroll
            for (int c = 0; c < 2; ++c)
#pragma unroll
                for (int r = 0; r < 16; ++r) acc[a][c][r] = 0.f;

        for (int dc = 0; dc < 4; ++dc) {
            __syncthreads();
            stage_swz(Qs, Qb, q0, dc * 64, w, l);
            stage_swz(Ks, Kb, k0, dc * 64, w, l);
            __syncthreads();
#pragma unroll
            for (int ks = 0; ks < 4; ++ks) {
                int u = ks * 2 + hi;
                short8_t a0 = frd(Qs, rq + 0, lo, u);
                short8_t a1 = frd(Qs, rq + 1, lo, u);
                short8_t b0 = frd(Ks, rk + 0, lo, u);
                short8_t b1 = frd(Ks, rk + 1, lo, u);
                acc[0][0] = MFMA(a0, b0, acc[0][0]);
                acc[0][1] = MFMA(a0, b1, acc[0][1]);
                acc[1][0] = MFMA(a1, b0, acc[1][0]);
                acc[1][1] = MFMA(a1, b1, acc[1][1]);
            }
        }
#pragma unroll
        for (int mb = 0; mb < 2; ++mb)
#pragma unroll
            for (int r = 0; r < 16; ++r)
                rs[mb][r] += __expf(acc[mb][0][r] * SCALE) + __expf(acc[mb][1][r] * SCALE);
    }
    __syncthreads();
#pragma unroll
    for (int mb = 0; mb < 2; ++mb)
#pragma unroll
        for (int r = 0; r < 16; ++r) {
            int row = (w & 1) * 64 + mb * 32 + (r & 3) + 8 * (r >> 2) + 4 * hi;
            red[row * 66 + (w >> 1) * 32 + lo] = rs[mb][r];
        }
    __syncthreads();
    if (t < 128) {
        float s = 0.f;
#pragma unroll 8
        for (int j = 0; j < 64; ++j) s += red[t * 66 + j];
        atomicAdd(&lsum[b * NTOK + q0 + t], s);
    }
}

// ---------------- pass 2 (VERBATIM R7-validated): w[b,k] += sum_q exp(scale*s)/l_q ----------------
__global__ __launch_bounds__(256) void score_pass2(const unsigned short* __restrict__ Qbf,
                                                   const unsigned short* __restrict__ Kbf,
                                                   const float* __restrict__ lsum,
                                                   float* __restrict__ wsum) {
    const int b = blockIdx.z;
    const int k0 = blockIdx.x * 128;
    const int qslice = blockIdx.y;
    const int t = threadIdx.x, w = t >> 6, l = t & 63, lo = l & 31, hi = l >> 5;
    const int rq = (w & 1) * 2, rk = (w >> 1) * 2;
    const unsigned short* Qb = Qbf + (size_t)b * NTOK * HDIM;
    const unsigned short* Kb = Kbf + (size_t)b * NTOK * HDIM;

    __shared__ __align__(16) char smem[33792];
    __shared__ float linv_s[128];
    unsigned short* Qs = (unsigned short*)smem;
    unsigned short* Ks = Qs + 8192;
    float* red2 = (float*)smem;

    float cs0 = 0.f, cs1 = 0.f;

    for (int qt = 0; qt < 4; ++qt) {
        const int q0 = qslice * 512 + qt * 128;
        f32x16 acc[2][2];
#pragma unroll
        for (int a = 0; a < 2; ++a)
#pragma unroll
            for (int c = 0; c < 2; ++c)
#pragma unroll
                for (int r = 0; r < 16; ++r) acc[a][c][r] = 0.f;

        for (int dc = 0; dc < 4; ++dc) {
            __syncthreads();
            stage_swz(Qs, Qb, q0, dc * 64, w, l);
            stage_swz(Ks, Kb, k0, dc * 64, w, l);
            if (dc == 0 && t < 128) linv_s[t] = 1.0f / lsum[b * NTOK + q0 + t];
            __syncthreads();
#pragma unroll
            for (int ks = 0; ks < 4; ++ks) {
                int u = ks * 2 + hi;
                short8_t a0 = frd(Qs, rq + 0, lo, u);
                short8_t a1 = frd(Qs, rq + 1, lo, u);
                short8_t b0 = frd(Ks, rk + 0, lo, u);
                short8_t b1 = frd(Ks, rk + 1, lo, u);
                acc[0][0] = MFMA(a0, b0, acc[0][0]);
                acc[0][1] = MFMA(a0, b1, acc[0][1]);
                acc[1][0] = MFMA(a1, b0, acc[1][0]);
                acc[1][1] = MFMA(a1, b1, acc[1][1]);
            }
        }
#pragma unroll
        for (int mb = 0; mb < 2; ++mb)
#pragma unroll
            for (int r = 0; r < 16; ++r) {
                float li = linv_s[(w & 1) * 64 + mb * 32 + (r & 3) + 8 * (r >> 2) + 4 * hi];
                cs0 += __expf(acc[mb][0][r] * SCALE) * li;
                cs1 += __expf(acc[mb][1][r] * SCALE) * li;
            }
    }
    __syncthreads();
    red2[((w >> 1) * 64 + lo) * 5 + (w & 1) * 2 + hi] = cs0;
    red2[((w >> 1) * 64 + 32 + lo) * 5 + (w & 1) * 2 + hi] = cs1;
    __syncthreads();
    if (t < 128) {
        float s = red2[t * 5 + 0] + red2[t * 5 + 1] + red2[t * 5 + 2] + red2[t * 5 + 3];
        atomicAdd(&wsum[b * NTOK + k0 + t], s);
    }
}

__global__ __launch_bounds__(256) void finalize_kernel(const float* __restrict__ V,
                                                       const float* __restrict__ w,
                                                       float* __restrict__ out) {
    const int b = blockIdx.y;
    const int k0 = blockIdx.x * 256;
    const int h = threadIdx.x;
    __shared__ float wsh[256];
    wsh[h] = w[b * NTOK + k0 + h];
    __syncthreads();
    const float* Vb = V + ((size_t)b * NTOK + k0) * HDIM;
    float acc = 0.f;
#pragma unroll 4
    for (int kk = 0; kk < 256; ++kk) acc = fmaf(wsh[kk], Vb[(size_t)kk * HDIM + h], acc);
    atomicAdd(&out[b * HDIM + h], acc * (1.0f / (float)NTOK));
}

extern "C" void kernel_launch(void* const* d_in, const int* in_sizes, int n_in,
                              void* d_out, int out_size, void* d_ws, size_t ws_size,
                              hipStream_t stream) {
    const float* x  = (const float*)d_in[0];
    const float* Wq = (const float*)d_in[1];
    const float* bq = (const float*)d_in[2];
    const float* Wk = (const float*)d_in[3];
    const float* bk = (const float*)d_in[4];
    const float* Wv = (const float*)d_in[5];
    const float* bv = (const float*)d_in[6];
    float* out = (float*)d_out;

    const size_t BNH = (size_t)NBATCH * NTOK * HDIM;   // 8388608
    unsigned short* Wt  = (unsigned short*)d_ws;        // 3 transposed bf16 weights
    unsigned short* xbf = Wt + 3 * 65536;               // bf16 x
    unsigned short* Qbf = xbf + BNH;
    unsigned short* Kbf = Qbf + BNH;
    float* Vf   = (float*)(Kbf + BNH);                  // fp32 V
    float* lsum = Vf + BNH;
    float* wsum = lsum + (size_t)NBATCH * NTOK;

    zero_kernel<<<dim3(128), dim3(256), 0, stream>>>(wsum, lsum, out);
    convert_x<<<dim3(8192), dim3(256), 0, stream>>>(x, xbf);
    convert_wt<<<dim3(8, 3), dim3(256), 0, stream>>>(Wq, Wk, Wv, Wt);
    qkv_mfma<<<dim3(256, 2, 3), dim3(256), 0, stream>>>(xbf, Wt, bq, bk, bv, Qbf, Kbf, Vf);
    score_pass1<<<dim3(32, 8, 8), dim3(256), 0, stream>>>(Qbf, Kbf, lsum);
    score_pass2<<<dim3(32, 8, 8), dim3(256), 0, stream>>>(Qbf, Kbf, lsum, wsum);
    finalize_kernel<<<dim3(16, 8), dim3(256), 0, stream>>>(Vf, wsum, out);
}